// Round 11
// baseline (2096.286 us; speedup 1.0000x reference)
//
#include <hip/hip_runtime.h>
#include <hip/hip_bf16.h>

// ---------------------------------------------------------------------------
// HybridCnnLnn R11 = R10 skeleton (proven absmax 0.0, no spill) + issue-cycle
// reduction. R10 counters: VALUBusy 77% of 1153us = 888us pure issue ->
// issue-bound. Changes:
//  1) packed fp32: per-cell math on <2 x float> (the 2 batches) -> v_pk_fma
//  2) folded sigmoid arg: z = r2 - r1*v (tables store (r1,r2)); sensory
//     folds in_w/in_b -> z = s2 - s1*f
//  3) serial v-update: IEEE div -> NR-refined rcp (shorter serial chain)
// Mapping/barriers/reduction identical to R10.
// ---------------------------------------------------------------------------

#define L2E 1.4426950408889634f

typedef float v2f __attribute__((ext_vector_type(2)));

__device__ __forceinline__ v2f splat(float s) { return (v2f){s, s}; }

// ---------------- prep: fold params, native [i][j] layout (identity) -------
__global__ __launch_bounds__(256)
void prep_kernel(const float* __restrict__ smu, const float* __restrict__ ssig,
                 const float* __restrict__ sW,  const float* __restrict__ serev,
                 const float* __restrict__ mu,  const float* __restrict__ sig,
                 const float* __restrict__ W,   const float* __restrict__ erev,
                 const float* __restrict__ in_w, const float* __restrict__ in_b,
                 float2* __restrict__ R12, float* __restrict__ VT,
                 float2* __restrict__ S2,  float* __restrict__ SV) {
  int idx = blockIdx.x * 256 + threadIdx.x;      // 64 blocks x 256 = 16384
  int i = idx >> 7;
  float r1 = sig[idx] * L2E;
  R12[idx] = make_float2(r1, mu[idx] * r1);      // z = r2 - r1*v
  VT[idx]  = W[idx] * erev[idx];                 // |erev|=1 -> |VT| = W
  float ss = ssig[idx] * L2E;
  S2[idx]  = make_float2(ss * in_w[i], (smu[idx] - in_b[i]) * ss);  // z = s2 - s1*f
  SV[idx]  = sW[idx] * serev[idx];
}

// ----------------------------- conv1 (k=5, tiled) --------------------------
// x [512,256,24] -> P1 [512,64,128] ([b][co][t']), relu+maxpool2 fused
__launch_bounds__(512)
__global__ void conv1_kernel(const float* __restrict__ x, const float* __restrict__ w1,
                             const float* __restrict__ b1, float* __restrict__ P1) {
  __shared__ float xs[6240];                     // rows t in [-2,258), 24 ch
  int tid = threadIdx.x, b = blockIdx.x;
  const float* xb = x + (size_t)b * 6144;
  for (int idx = tid; idx < 6144; idx += 512) xs[idx + 48] = xb[idx];
  if (tid < 48) { xs[tid] = 0.f; xs[6192 + tid] = 0.f; }
  __syncthreads();
  int tp = tid & 127, cq = tid >> 7;             // 128 pooled t x 4 co-quarters
  float acc0[16], acc1[16];
#pragma unroll
  for (int n = 0; n < 16; n++) { float bb = b1[cq * 16 + n]; acc0[n] = bb; acc1[n] = bb; }
  for (int cic = 0; cic < 3; cic++) {            // ci chunks of 8
    float p[6][8];
#pragma unroll
    for (int r = 0; r < 6; r++) {
      const float* row = &xs[(2 * tp + r) * 24 + cic * 8];
      float4 a = *(const float4*)row;
      float4 c = *(const float4*)(row + 4);
      p[r][0] = a.x; p[r][1] = a.y; p[r][2] = a.z; p[r][3] = a.w;
      p[r][4] = c.x; p[r][5] = c.y; p[r][6] = c.z; p[r][7] = c.w;
    }
#pragma unroll
    for (int n = 0; n < 16; n++) {
      const float* wr = w1 + (cq * 16 + n) * 120 + cic * 40;  // uniform -> s_load
#pragma unroll
      for (int c = 0; c < 8; c++) {
#pragma unroll
        for (int kk = 0; kk < 5; kk++) {
          float w = wr[c * 5 + kk];
          acc0[n] = fmaf(p[kk][c],     w, acc0[n]);
          acc1[n] = fmaf(p[kk + 1][c], w, acc1[n]);
        }
      }
    }
  }
  float* pb = P1 + (size_t)b * 8192;
#pragma unroll
  for (int n = 0; n < 16; n++)
    pb[(cq * 16 + n) * 128 + tp] = fmaxf(fmaxf(acc0[n], acc1[n]), 0.f);
}

// ----------------------------- conv2 (k=3, tiled) --------------------------
// P1 [512,64,128] -> feats [512,64,128] laid out [b][t'][co]
__launch_bounds__(512)
__global__ void conv2_kernel(const float* __restrict__ P1, const float* __restrict__ w2,
                             const float* __restrict__ b2, float* __restrict__ feats) {
  __shared__ float xs[8450];                     // [t+1][ci], stride 65
  int tid = threadIdx.x, b = blockIdx.x;
  const float* pb = P1 + (size_t)b * 8192;
  for (int idx = tid; idx < 8192; idx += 512) {
    int ci = idx >> 7, t = idx & 127;
    xs[(t + 1) * 65 + ci] = pb[idx];
  }
  if (tid < 65) { xs[tid] = 0.f; xs[129 * 65 + tid] = 0.f; }
  __syncthreads();
  int tp = tid & 63, cq = tid >> 6;              // 64 pooled t x 8 co-octants
  float acc0[16], acc1[16];
#pragma unroll
  for (int n = 0; n < 16; n++) { float bb = b2[cq * 16 + n]; acc0[n] = bb; acc1[n] = bb; }
  for (int cic = 0; cic < 8; cic++) {            // ci chunks of 8
    float p[4][8];
#pragma unroll
    for (int r = 0; r < 4; r++)
#pragma unroll
      for (int c = 0; c < 8; c++)
        p[r][c] = xs[(2 * tp + r) * 65 + cic * 8 + c];
#pragma unroll
    for (int n = 0; n < 16; n++) {
      const float* wr = w2 + (cq * 16 + n) * 192 + cic * 24;  // native [co][ci][kk]
#pragma unroll
      for (int c = 0; c < 8; c++) {
#pragma unroll
        for (int kk = 0; kk < 3; kk++) {
          float w = wr[c * 3 + kk];
          acc0[n] = fmaf(p[kk][c],     w, acc0[n]);
          acc1[n] = fmaf(p[kk + 1][c], w, acc1[n]);
        }
      }
    }
  }
  __syncthreads();                               // reuse xs as [tp][co]
#pragma unroll
  for (int n = 0; n < 16; n += 4) {
    float4 v;
    v.x = fmaxf(fmaxf(acc0[n],     acc1[n]),     0.f);
    v.y = fmaxf(fmaxf(acc0[n + 1], acc1[n + 1]), 0.f);
    v.z = fmaxf(fmaxf(acc0[n + 2], acc1[n + 2]), 0.f);
    v.w = fmaxf(fmaxf(acc0[n + 3], acc1[n + 3]), 0.f);
    *(float4*)&xs[tp * 128 + cq * 16 + n] = v;
  }
  __syncthreads();
  float* fb = feats + (size_t)b * 8192;
  for (int idx = tid; idx < 8192; idx += 512) fb[idx] = xs[idx];
}

// --------------------------- LTC recurrence + head -------------------------
// block = 1024 threads: j = tid&127 (unit), h = tid>>7 (i-octant).
// 2 batches/block (packed as v2f lanes), grid 256 = 1 block/CU.
// (r1,r2) in LDS; vw in 16 VGPRs; sensory S2/SV streamed from L2 per t.
__launch_bounds__(1024)
__global__ void lnn_kernel(const float2* __restrict__ R12, const float* __restrict__ VT,
                           const float2* __restrict__ S2,  const float* __restrict__ SV,
                           const float* __restrict__ feats,
                           const float* __restrict__ cm_t, const float* __restrict__ gleak,
                           const float* __restrict__ vleak,
                           const float* __restrict__ fc1_w, const float* __restrict__ fc1_b,
                           const float* __restrict__ fc2_w, const float* __restrict__ fc2_b,
                           float* __restrict__ out) {
  __shared__ v2f r12lds[16384];                  // 128KB: (r1, r2)[i][j]
  __shared__ float4 psum[8][128];                // 16KB
  __shared__ v2f vs2[128];
  __shared__ v2f xt2[128];
  __shared__ float red[2][64];
  int tid = threadIdx.x;
  int j = tid & 127, h = tid >> 7;               // h in [0,8)
  int b0 = blockIdx.x * 2;

  // stage (r1,r2) table into LDS (16 coalesced b64 iters)
  for (int idx = tid; idx < 16384; idx += 1024) {
    float2 r = R12[idx];
    r12lds[idx] = (v2f){r.x, r.y};
  }

  // vw -> VGPRs (16 regs; coalesced over j)
  float vw[16];
#pragma unroll
  for (int n = 0; n < 16; n++) vw[n] = VT[(16 * h + n) * 128 + j];

  float cmj = cm_t[j], glk = gleak[j];
  float gvl = glk * vleak[j], cgl = cmj + glk;
  float vj0 = 0.f, vj1 = 0.f;
  if (tid < 128) vs2[j] = (v2f){0.f, 0.f};
  __syncthreads();

  for (int t = 0; t < 64; t++) {
    // stage raw features for both batches (affine folded into S2 tables)
    if (tid < 128) {
      float a = feats[(size_t)b0 * 8192 + t * 128 + j];
      float b = feats[(size_t)(b0 + 1) * 8192 + t * 128 + j];
      xt2[j] = (v2f){a, b};
    }
    __syncthreads();

    // ---- sensory partials (S2 + SV streamed from L2) ----
    float sn0 = 0.f, sd0 = 0.f, sn1 = 0.f, sd1 = 0.f;
    {
      v2f nacc = {0.f, 0.f}, dacc = {0.f, 0.f};
      const float2* sp = S2 + (size_t)(16 * h) * 128 + j;
      const float*  vp = SV + (size_t)(16 * h) * 128 + j;
#pragma unroll
      for (int n = 0; n < 16; n++) {
        float2 s = sp[n * 128];
        float svv = vp[n * 128];
        v2f f01 = xt2[16 * h + n];
        v2f z = __builtin_elementwise_fma(f01, splat(-s.x), splat(s.y));
        v2f e = {__builtin_amdgcn_exp2f(z.x), __builtin_amdgcn_exp2f(z.y)};
        e = e + splat(1.f);
        v2f q = {__builtin_amdgcn_rcpf(e.x), __builtin_amdgcn_rcpf(e.y)};
        nacc = __builtin_elementwise_fma(splat(svv), q, nacc);
        dacc = __builtin_elementwise_fma(splat(fabsf(svv)), q, dacc);
      }
      psum[h][j] = make_float4(nacc.x, dacc.x, nacc.y, dacc.y);
    }
    __syncthreads();
    if (h == 0) {                                // wave-uniform branch
      float4 a0 = psum[0][j], a1 = psum[1][j], a2 = psum[2][j], a3 = psum[3][j];
      float4 a4 = psum[4][j], a5 = psum[5][j], a6 = psum[6][j], a7 = psum[7][j];
      sn0 = a0.x + a1.x + a2.x + a3.x + a4.x + a5.x + a6.x + a7.x;
      sd0 = a0.y + a1.y + a2.y + a3.y + a4.y + a5.y + a6.y + a7.y;
      sn1 = a0.z + a1.z + a2.z + a3.z + a4.z + a5.z + a6.z + a7.z;
      sd1 = a0.w + a1.w + a2.w + a3.w + a4.w + a5.w + a6.w + a7.w;
    }
    __syncthreads();                             // psum reusable after this

    // ---- 6 semi-implicit ODE unfolds ((r1,r2) from LDS, vw in VGPRs) ----
    for (int u = 0; u < 6; u++) {
      v2f nacc = {0.f, 0.f}, dacc = {0.f, 0.f};
      const v2f* mp = &r12lds[(16 * h) * 128 + j];
#pragma unroll
      for (int n = 0; n < 16; n++) {
        v2f rr = mp[n * 128];                    // stride-8B b64, conflict-free
        v2f v01 = vs2[16 * h + n];               // broadcast read
        v2f z = __builtin_elementwise_fma(v01, splat(-rr.x), splat(rr.y));
        v2f e = {__builtin_amdgcn_exp2f(z.x), __builtin_amdgcn_exp2f(z.y)};
        e = e + splat(1.f);
        v2f q = {__builtin_amdgcn_rcpf(e.x), __builtin_amdgcn_rcpf(e.y)};
        nacc = __builtin_elementwise_fma(splat(vw[n]), q, nacc);
        dacc = __builtin_elementwise_fma(splat(fabsf(vw[n])), q, dacc);
      }
      psum[h][j] = make_float4(nacc.x, dacc.x, nacc.y, dacc.y);
      __syncthreads();
      if (h == 0) {                              // wave-uniform
        float4 a0 = psum[0][j], a1 = psum[1][j], a2 = psum[2][j], a3 = psum[3][j];
        float4 a4 = psum[4][j], a5 = psum[5][j], a6 = psum[6][j], a7 = psum[7][j];
        float wn0 = sn0 + a0.x + a1.x + a2.x + a3.x + a4.x + a5.x + a6.x + a7.x;
        float wd0 = sd0 + a0.y + a1.y + a2.y + a3.y + a4.y + a5.y + a6.y + a7.y;
        float wn1 = sn1 + a0.z + a1.z + a2.z + a3.z + a4.z + a5.z + a6.z + a7.z;
        float wd1 = sd1 + a0.w + a1.w + a2.w + a3.w + a4.w + a5.w + a6.w + a7.w;
        // NR-refined rcp (den > 1.5 always; ~1-2ulp vs IEEE div)
        float den0 = cgl + wd0, den1 = cgl + wd1;
        float i0 = __builtin_amdgcn_rcpf(den0);
        i0 = i0 * fmaf(-den0, i0, 2.f);
        float i1 = __builtin_amdgcn_rcpf(den1);
        i1 = i1 * fmaf(-den1, i1, 2.f);
        vj0 = (fmaf(cmj, vj0, gvl) + wn0) * i0;
        vj1 = (fmaf(cmj, vj1, gvl) + wn1) * i1;
        vs2[j] = (v2f){vj0, vj1};
      }
      __syncthreads();
    }
  }

  // ---- MLP head (naive pattern: LDS red + sequential final sum) ----
  if (tid < 128) {
    int g = tid >> 6, d = tid & 63;
    float acc = fc1_b[d];
    for (int u = 0; u < 128; u++) {
      v2f v2 = vs2[u];
      acc = fmaf(g ? v2.y : v2.x, fc1_w[d * 128 + u], acc);
    }
    red[g][d] = fmaxf(acc, 0.f) * fc2_w[d];
  }
  __syncthreads();
  if (tid < 2) {
    float s = fc2_b[0];
    for (int d = 0; d < 64; d++) s += red[tid][d];
    out[b0 + tid] = s;
  }
}

// ------------------------------- launcher ----------------------------------
extern "C" void kernel_launch(void* const* d_in, const int* in_sizes, int n_in,
                              void* d_out, int out_size, void* d_ws, size_t ws_size,
                              hipStream_t stream) {
  (void)in_sizes; (void)n_in; (void)out_size; (void)ws_size;
  char* ws = (char*)d_ws;
  // Proven 32MB envelope, time-multiplexed:
  //   P1 [0,16M) live conv1->conv2; tables [0,384K) after conv2 (prep);
  //   feats [16M,32M) live conv2->lnn.
  float*  P1   = (float*)(ws);
  float*  feats= (float*)(ws + (16 << 20));
  float2* R12  = (float2*)(ws + 0);             // 128KB
  float*  VT   = (float*)(ws + (128 << 10));    // 64KB
  float2* S2   = (float2*)(ws + (192 << 10));   // 128KB
  float*  SV   = (float*)(ws + (320 << 10));    // 64KB -> ends 384KB

  conv1_kernel<<<512, 512, 0, stream>>>((const float*)d_in[0],
      (const float*)d_in[1], (const float*)d_in[2], P1);
  conv2_kernel<<<512, 512, 0, stream>>>(P1,
      (const float*)d_in[3], (const float*)d_in[4], feats);
  prep_kernel<<<64, 256, 0, stream>>>(
      (const float*)d_in[7], (const float*)d_in[8],
      (const float*)d_in[9], (const float*)d_in[10],
      (const float*)d_in[11], (const float*)d_in[12],
      (const float*)d_in[13], (const float*)d_in[14],
      (const float*)d_in[5], (const float*)d_in[6],
      R12, VT, S2, SV);
  lnn_kernel<<<256, 1024, 0, stream>>>(R12, VT, S2, SV, feats,
      (const float*)d_in[17], (const float*)d_in[16], (const float*)d_in[15],
      (const float*)d_in[18], (const float*)d_in[19],
      (const float*)d_in[20], (const float*)d_in[21],
      (float*)d_out);
}

// Round 12
// 1483.110 us; speedup vs baseline: 1.4134x; 1.4134x over previous
//
#include <hip/hip_runtime.h>
#include <hip/hip_bf16.h>

// ---------------------------------------------------------------------------
// HybridCnnLnn R12 = R10 (proven: no spill, 1153us lnn) + 3 scalar changes:
//  1) folded sigmoid arg z = r2 - r1*v (one fma; tables store (r1,r2));
//     sensory folds in_w/in_b -> z = s2 - s1*f
//  2) redundant psum reduction across all h (kills the 1-wave-serial section)
//  3) NR-refined rcp for the v-update (shorter serial chain)
// R11 lesson (NEVER repeat): ext-vector v2f in the hot loop -> reg-pair
// pressure -> 3.8GB scratch spill. Scalar only.
// Trans floor: 2 trans/cell x 8cy = 382us/SIMD busy; total scalar ideal
// ~530us; rest is overhead + barriers.
// ---------------------------------------------------------------------------

#define L2E 1.4426950408889634f

// ---------------- prep: fold params, native [i][j] layout (identity) -------
__global__ __launch_bounds__(256)
void prep_kernel(const float* __restrict__ smu, const float* __restrict__ ssig,
                 const float* __restrict__ sW,  const float* __restrict__ serev,
                 const float* __restrict__ mu,  const float* __restrict__ sig,
                 const float* __restrict__ W,   const float* __restrict__ erev,
                 const float* __restrict__ in_w, const float* __restrict__ in_b,
                 float2* __restrict__ R12, float* __restrict__ VT,
                 float2* __restrict__ S2,  float* __restrict__ SV) {
  int idx = blockIdx.x * 256 + threadIdx.x;      // 64 blocks x 256 = 16384
  int i = idx >> 7;
  float r1 = sig[idx] * L2E;
  R12[idx] = make_float2(r1, mu[idx] * r1);      // z = r2 - r1*v
  VT[idx]  = W[idx] * erev[idx];                 // |erev|=1 -> |VT| = W
  float ss = ssig[idx] * L2E;
  S2[idx]  = make_float2(ss * in_w[i], (smu[idx] - in_b[i]) * ss);  // z = s2 - s1*f
  SV[idx]  = sW[idx] * serev[idx];
}

// ----------------------------- conv1 (k=5, tiled) --------------------------
// x [512,256,24] -> P1 [512,64,128] ([b][co][t']), relu+maxpool2 fused
__launch_bounds__(512)
__global__ void conv1_kernel(const float* __restrict__ x, const float* __restrict__ w1,
                             const float* __restrict__ b1, float* __restrict__ P1) {
  __shared__ float xs[6240];                     // rows t in [-2,258), 24 ch
  int tid = threadIdx.x, b = blockIdx.x;
  const float* xb = x + (size_t)b * 6144;
  for (int idx = tid; idx < 6144; idx += 512) xs[idx + 48] = xb[idx];
  if (tid < 48) { xs[tid] = 0.f; xs[6192 + tid] = 0.f; }
  __syncthreads();
  int tp = tid & 127, cq = tid >> 7;             // 128 pooled t x 4 co-quarters
  float acc0[16], acc1[16];
#pragma unroll
  for (int n = 0; n < 16; n++) { float bb = b1[cq * 16 + n]; acc0[n] = bb; acc1[n] = bb; }
  for (int cic = 0; cic < 3; cic++) {            // ci chunks of 8
    float p[6][8];
#pragma unroll
    for (int r = 0; r < 6; r++) {
      const float* row = &xs[(2 * tp + r) * 24 + cic * 8];
      float4 a = *(const float4*)row;
      float4 c = *(const float4*)(row + 4);
      p[r][0] = a.x; p[r][1] = a.y; p[r][2] = a.z; p[r][3] = a.w;
      p[r][4] = c.x; p[r][5] = c.y; p[r][6] = c.z; p[r][7] = c.w;
    }
#pragma unroll
    for (int n = 0; n < 16; n++) {
      const float* wr = w1 + (cq * 16 + n) * 120 + cic * 40;  // uniform -> s_load
#pragma unroll
      for (int c = 0; c < 8; c++) {
#pragma unroll
        for (int kk = 0; kk < 5; kk++) {
          float w = wr[c * 5 + kk];
          acc0[n] = fmaf(p[kk][c],     w, acc0[n]);
          acc1[n] = fmaf(p[kk + 1][c], w, acc1[n]);
        }
      }
    }
  }
  float* pb = P1 + (size_t)b * 8192;
#pragma unroll
  for (int n = 0; n < 16; n++)
    pb[(cq * 16 + n) * 128 + tp] = fmaxf(fmaxf(acc0[n], acc1[n]), 0.f);
}

// ----------------------------- conv2 (k=3, tiled) --------------------------
// P1 [512,64,128] -> feats [512,64,128] laid out [b][t'][co]
__launch_bounds__(512)
__global__ void conv2_kernel(const float* __restrict__ P1, const float* __restrict__ w2,
                             const float* __restrict__ b2, float* __restrict__ feats) {
  __shared__ float xs[8450];                     // [t+1][ci], stride 65
  int tid = threadIdx.x, b = blockIdx.x;
  const float* pb = P1 + (size_t)b * 8192;
  for (int idx = tid; idx < 8192; idx += 512) {
    int ci = idx >> 7, t = idx & 127;
    xs[(t + 1) * 65 + ci] = pb[idx];
  }
  if (tid < 65) { xs[tid] = 0.f; xs[129 * 65 + tid] = 0.f; }
  __syncthreads();
  int tp = tid & 63, cq = tid >> 6;              // 64 pooled t x 8 co-octants
  float acc0[16], acc1[16];
#pragma unroll
  for (int n = 0; n < 16; n++) { float bb = b2[cq * 16 + n]; acc0[n] = bb; acc1[n] = bb; }
  for (int cic = 0; cic < 8; cic++) {            // ci chunks of 8
    float p[4][8];
#pragma unroll
    for (int r = 0; r < 4; r++)
#pragma unroll
      for (int c = 0; c < 8; c++)
        p[r][c] = xs[(2 * tp + r) * 65 + cic * 8 + c];
#pragma unroll
    for (int n = 0; n < 16; n++) {
      const float* wr = w2 + (cq * 16 + n) * 192 + cic * 24;  // native [co][ci][kk]
#pragma unroll
      for (int c = 0; c < 8; c++) {
#pragma unroll
        for (int kk = 0; kk < 3; kk++) {
          float w = wr[c * 3 + kk];
          acc0[n] = fmaf(p[kk][c],     w, acc0[n]);
          acc1[n] = fmaf(p[kk + 1][c], w, acc1[n]);
        }
      }
    }
  }
  __syncthreads();                               // reuse xs as [tp][co]
#pragma unroll
  for (int n = 0; n < 16; n += 4) {
    float4 v;
    v.x = fmaxf(fmaxf(acc0[n],     acc1[n]),     0.f);
    v.y = fmaxf(fmaxf(acc0[n + 1], acc1[n + 1]), 0.f);
    v.z = fmaxf(fmaxf(acc0[n + 2], acc1[n + 2]), 0.f);
    v.w = fmaxf(fmaxf(acc0[n + 3], acc1[n + 3]), 0.f);
    *(float4*)&xs[tp * 128 + cq * 16 + n] = v;
  }
  __syncthreads();
  float* fb = feats + (size_t)b * 8192;
  for (int idx = tid; idx < 8192; idx += 512) fb[idx] = xs[idx];
}

// --------------------------- LTC recurrence + head -------------------------
// block = 1024 threads: j = tid&127 (unit), h = tid>>7 (i-octant).
// 2 batches/block, grid 256 = 1 block/CU. (r1,r2) in LDS; vw in 16 VGPRs;
// sensory S2/SV streamed from L2. ALL threads reduce psum redundantly
// (bitwise-identical vj across h; h==0 slice writes vs2).
__launch_bounds__(1024)
__global__ void lnn_kernel(const float2* __restrict__ R12, const float* __restrict__ VT,
                           const float2* __restrict__ S2,  const float* __restrict__ SV,
                           const float* __restrict__ feats,
                           const float* __restrict__ cm_t, const float* __restrict__ gleak,
                           const float* __restrict__ vleak,
                           const float* __restrict__ fc1_w, const float* __restrict__ fc1_b,
                           const float* __restrict__ fc2_w, const float* __restrict__ fc2_b,
                           float* __restrict__ out) {
  __shared__ float2 r12lds[16384];               // 128KB: (r1, r2)[i][j]
  __shared__ float4 psum[8][128];                // 16KB
  __shared__ float2 vs2[128];
  __shared__ float2 xt2[128];
  __shared__ float red[2][64];
  int tid = threadIdx.x;
  int j = tid & 127, h = tid >> 7;               // h in [0,8)
  int b0 = blockIdx.x * 2;

  // stage (r1,r2) table into LDS (16 coalesced float2 iters)
  for (int idx = tid; idx < 16384; idx += 1024) r12lds[idx] = R12[idx];

  // vw -> VGPRs (16 regs; coalesced over j)
  float vw[16];
#pragma unroll
  for (int n = 0; n < 16; n++) vw[n] = VT[(16 * h + n) * 128 + j];

  float cmj = cm_t[j], glk = gleak[j];
  float gvl = glk * vleak[j], cgl = cmj + glk;
  float vj0 = 0.f, vj1 = 0.f;                    // replicated across h
  if (tid < 128) vs2[j] = make_float2(0.f, 0.f);
  __syncthreads();

  for (int t = 0; t < 64; t++) {
    // stage raw features for both batches (affine folded into S2 tables)
    if (tid < 128) {
      float a = feats[(size_t)b0 * 8192 + t * 128 + j];
      float b = feats[(size_t)(b0 + 1) * 8192 + t * 128 + j];
      xt2[j] = make_float2(a, b);
    }
    __syncthreads();

    // ---- sensory partials (S2 + SV streamed from L2) ----
    float sn0, sd0, sn1, sd1;
    {
      float n0 = 0.f, d0 = 0.f, n1 = 0.f, d1 = 0.f;
      const float2* sp = S2 + (size_t)(16 * h) * 128 + j;
      const float*  vp = SV + (size_t)(16 * h) * 128 + j;
#pragma unroll
      for (int n = 0; n < 16; n++) {
        float2 s = sp[n * 128];
        float svv = vp[n * 128];
        float2 xv = xt2[16 * h + n];
        float q0 = __builtin_amdgcn_rcpf(1.f + __builtin_amdgcn_exp2f(fmaf(-s.x, xv.x, s.y)));
        n0 = fmaf(svv, q0, n0); d0 = fmaf(fabsf(svv), q0, d0);
        float q1 = __builtin_amdgcn_rcpf(1.f + __builtin_amdgcn_exp2f(fmaf(-s.x, xv.y, s.y)));
        n1 = fmaf(svv, q1, n1); d1 = fmaf(fabsf(svv), q1, d1);
      }
      psum[h][j] = make_float4(n0, d0, n1, d1);
    }
    __syncthreads();
    {                                            // redundant reduce (all h)
      float4 a0 = psum[0][j], a1 = psum[1][j], a2 = psum[2][j], a3 = psum[3][j];
      float4 a4 = psum[4][j], a5 = psum[5][j], a6 = psum[6][j], a7 = psum[7][j];
      sn0 = a0.x + a1.x + a2.x + a3.x + a4.x + a5.x + a6.x + a7.x;
      sd0 = a0.y + a1.y + a2.y + a3.y + a4.y + a5.y + a6.y + a7.y;
      sn1 = a0.z + a1.z + a2.z + a3.z + a4.z + a5.z + a6.z + a7.z;
      sd1 = a0.w + a1.w + a2.w + a3.w + a4.w + a5.w + a6.w + a7.w;
    }
    __syncthreads();                             // psum reusable after this

    // ---- 6 semi-implicit ODE unfolds ((r1,r2) from LDS, vw in VGPRs) ----
    for (int u = 0; u < 6; u++) {
      float n0 = 0.f, d0 = 0.f, n1 = 0.f, d1 = 0.f;
      const float2* mp = &r12lds[(16 * h) * 128 + j];
#pragma unroll
      for (int n = 0; n < 16; n++) {
        float2 rr = mp[n * 128];                 // stride-8B b64, conflict-free
        float2 v2 = vs2[16 * h + n];             // broadcast read
        float q0 = __builtin_amdgcn_rcpf(1.f + __builtin_amdgcn_exp2f(fmaf(-rr.x, v2.x, rr.y)));
        n0 = fmaf(vw[n], q0, n0); d0 = fmaf(fabsf(vw[n]), q0, d0);
        float q1 = __builtin_amdgcn_rcpf(1.f + __builtin_amdgcn_exp2f(fmaf(-rr.x, v2.y, rr.y)));
        n1 = fmaf(vw[n], q1, n1); d1 = fmaf(fabsf(vw[n]), q1, d1);
      }
      psum[h][j] = make_float4(n0, d0, n1, d1);
      __syncthreads();
      {                                          // redundant reduce (all h)
        float4 a0 = psum[0][j], a1 = psum[1][j], a2 = psum[2][j], a3 = psum[3][j];
        float4 a4 = psum[4][j], a5 = psum[5][j], a6 = psum[6][j], a7 = psum[7][j];
        float wn0 = sn0 + a0.x + a1.x + a2.x + a3.x + a4.x + a5.x + a6.x + a7.x;
        float wd0 = sd0 + a0.y + a1.y + a2.y + a3.y + a4.y + a5.y + a6.y + a7.y;
        float wn1 = sn1 + a0.z + a1.z + a2.z + a3.z + a4.z + a5.z + a6.z + a7.z;
        float wd1 = sd1 + a0.w + a1.w + a2.w + a3.w + a4.w + a5.w + a6.w + a7.w;
        // NR-refined rcp (den > 1.5 always; ~1ulp)
        float den0 = cgl + wd0, den1 = cgl + wd1;
        float i0 = __builtin_amdgcn_rcpf(den0); i0 = i0 * fmaf(-den0, i0, 2.f);
        float i1 = __builtin_amdgcn_rcpf(den1); i1 = i1 * fmaf(-den1, i1, 2.f);
        vj0 = (fmaf(cmj, vj0, gvl) + wn0) * i0;  // identical across h
        vj1 = (fmaf(cmj, vj1, gvl) + wn1) * i1;
        if (tid < 128) vs2[j] = make_float2(vj0, vj1);
      }
      __syncthreads();
    }
  }

  // ---- MLP head (naive pattern: LDS red + sequential final sum) ----
  if (tid < 128) {
    int g = tid >> 6, d = tid & 63;
    float acc = fc1_b[d];
    for (int u = 0; u < 128; u++) {
      float2 v2 = vs2[u];
      acc = fmaf(g ? v2.y : v2.x, fc1_w[d * 128 + u], acc);
    }
    red[g][d] = fmaxf(acc, 0.f) * fc2_w[d];
  }
  __syncthreads();
  if (tid < 2) {
    float s = fc2_b[0];
    for (int d = 0; d < 64; d++) s += red[tid][d];
    out[b0 + tid] = s;
  }
}

// ------------------------------- launcher ----------------------------------
extern "C" void kernel_launch(void* const* d_in, const int* in_sizes, int n_in,
                              void* d_out, int out_size, void* d_ws, size_t ws_size,
                              hipStream_t stream) {
  (void)in_sizes; (void)n_in; (void)out_size; (void)ws_size;
  char* ws = (char*)d_ws;
  // Proven 32MB envelope, time-multiplexed:
  //   P1 [0,16M) live conv1->conv2; tables [0,384K) after conv2 (prep);
  //   feats [16M,32M) live conv2->lnn.
  float*  P1   = (float*)(ws);
  float*  feats= (float*)(ws + (16 << 20));
  float2* R12  = (float2*)(ws + 0);             // 128KB
  float*  VT   = (float*)(ws + (128 << 10));    // 64KB
  float2* S2   = (float2*)(ws + (192 << 10));   // 128KB
  float*  SV   = (float*)(ws + (320 << 10));    // 64KB -> ends 384KB

  conv1_kernel<<<512, 512, 0, stream>>>((const float*)d_in[0],
      (const float*)d_in[1], (const float*)d_in[2], P1);
  conv2_kernel<<<512, 512, 0, stream>>>(P1,
      (const float*)d_in[3], (const float*)d_in[4], feats);
  prep_kernel<<<64, 256, 0, stream>>>(
      (const float*)d_in[7], (const float*)d_in[8],
      (const float*)d_in[9], (const float*)d_in[10],
      (const float*)d_in[11], (const float*)d_in[12],
      (const float*)d_in[13], (const float*)d_in[14],
      (const float*)d_in[5], (const float*)d_in[6],
      R12, VT, S2, SV);
  lnn_kernel<<<256, 1024, 0, stream>>>(R12, VT, S2, SV, feats,
      (const float*)d_in[17], (const float*)d_in[16], (const float*)d_in[15],
      (const float*)d_in[18], (const float*)d_in[19],
      (const float*)d_in[20], (const float*)d_in[21],
      (float*)d_out);
}

// Round 13
// 1399.854 us; speedup vs baseline: 1.4975x; 1.0595x over previous
//
#include <hip/hip_runtime.h>
#include <hip/hip_bf16.h>

// ---------------------------------------------------------------------------
// HybridCnnLnn R13 = R10 (proven: no spill, lnn 1153us) + 2 pressure-neutral
// changes only:
//  1) folded sigmoid arg z = fmaf(-r1, v, r2); sensory folds in_w/in_b
//  2) NR-refined rcp in the h==0 serial v-update
// Reduction/barriers/mapping bit-for-bit R10 (h==0-only reduce).
// Toxic list (measured): ext-vector v2f (R11: 3.8GB spill), replicated
// reduce state (R12: 259MB spill), any >64-VGPR live set.
// Trans floor 382us; ideal busy ~600us; R10 busy 888us.
// ---------------------------------------------------------------------------

#define L2E 1.4426950408889634f

// ---------------- prep: fold params, native [i][j] layout (identity) -------
__global__ __launch_bounds__(256)
void prep_kernel(const float* __restrict__ smu, const float* __restrict__ ssig,
                 const float* __restrict__ sW,  const float* __restrict__ serev,
                 const float* __restrict__ mu,  const float* __restrict__ sig,
                 const float* __restrict__ W,   const float* __restrict__ erev,
                 const float* __restrict__ in_w, const float* __restrict__ in_b,
                 float2* __restrict__ R12, float* __restrict__ VT,
                 float2* __restrict__ S2,  float* __restrict__ SV) {
  int idx = blockIdx.x * 256 + threadIdx.x;      // 64 blocks x 256 = 16384
  int i = idx >> 7;
  float r1 = sig[idx] * L2E;
  R12[idx] = make_float2(r1, mu[idx] * r1);      // z = r2 - r1*v
  VT[idx]  = W[idx] * erev[idx];                 // |erev|=1 -> |VT| = W
  float ss = ssig[idx] * L2E;
  S2[idx]  = make_float2(ss * in_w[i], (smu[idx] - in_b[i]) * ss);  // z = s2 - s1*f
  SV[idx]  = sW[idx] * serev[idx];
}

// ----------------------------- conv1 (k=5, tiled) --------------------------
// x [512,256,24] -> P1 [512,64,128] ([b][co][t']), relu+maxpool2 fused
__launch_bounds__(512)
__global__ void conv1_kernel(const float* __restrict__ x, const float* __restrict__ w1,
                             const float* __restrict__ b1, float* __restrict__ P1) {
  __shared__ float xs[6240];                     // rows t in [-2,258), 24 ch
  int tid = threadIdx.x, b = blockIdx.x;
  const float* xb = x + (size_t)b * 6144;
  for (int idx = tid; idx < 6144; idx += 512) xs[idx + 48] = xb[idx];
  if (tid < 48) { xs[tid] = 0.f; xs[6192 + tid] = 0.f; }
  __syncthreads();
  int tp = tid & 127, cq = tid >> 7;             // 128 pooled t x 4 co-quarters
  float acc0[16], acc1[16];
#pragma unroll
  for (int n = 0; n < 16; n++) { float bb = b1[cq * 16 + n]; acc0[n] = bb; acc1[n] = bb; }
  for (int cic = 0; cic < 3; cic++) {            // ci chunks of 8
    float p[6][8];
#pragma unroll
    for (int r = 0; r < 6; r++) {
      const float* row = &xs[(2 * tp + r) * 24 + cic * 8];
      float4 a = *(const float4*)row;
      float4 c = *(const float4*)(row + 4);
      p[r][0] = a.x; p[r][1] = a.y; p[r][2] = a.z; p[r][3] = a.w;
      p[r][4] = c.x; p[r][5] = c.y; p[r][6] = c.z; p[r][7] = c.w;
    }
#pragma unroll
    for (int n = 0; n < 16; n++) {
      const float* wr = w1 + (cq * 16 + n) * 120 + cic * 40;  // uniform -> s_load
#pragma unroll
      for (int c = 0; c < 8; c++) {
#pragma unroll
        for (int kk = 0; kk < 5; kk++) {
          float w = wr[c * 5 + kk];
          acc0[n] = fmaf(p[kk][c],     w, acc0[n]);
          acc1[n] = fmaf(p[kk + 1][c], w, acc1[n]);
        }
      }
    }
  }
  float* pb = P1 + (size_t)b * 8192;
#pragma unroll
  for (int n = 0; n < 16; n++)
    pb[(cq * 16 + n) * 128 + tp] = fmaxf(fmaxf(acc0[n], acc1[n]), 0.f);
}

// ----------------------------- conv2 (k=3, tiled) --------------------------
// P1 [512,64,128] -> feats [512,64,128] laid out [b][t'][co]
__launch_bounds__(512)
__global__ void conv2_kernel(const float* __restrict__ P1, const float* __restrict__ w2,
                             const float* __restrict__ b2, float* __restrict__ feats) {
  __shared__ float xs[8450];                     // [t+1][ci], stride 65
  int tid = threadIdx.x, b = blockIdx.x;
  const float* pb = P1 + (size_t)b * 8192;
  for (int idx = tid; idx < 8192; idx += 512) {
    int ci = idx >> 7, t = idx & 127;
    xs[(t + 1) * 65 + ci] = pb[idx];
  }
  if (tid < 65) { xs[tid] = 0.f; xs[129 * 65 + tid] = 0.f; }
  __syncthreads();
  int tp = tid & 63, cq = tid >> 6;              // 64 pooled t x 8 co-octants
  float acc0[16], acc1[16];
#pragma unroll
  for (int n = 0; n < 16; n++) { float bb = b2[cq * 16 + n]; acc0[n] = bb; acc1[n] = bb; }
  for (int cic = 0; cic < 8; cic++) {            // ci chunks of 8
    float p[4][8];
#pragma unroll
    for (int r = 0; r < 4; r++)
#pragma unroll
      for (int c = 0; c < 8; c++)
        p[r][c] = xs[(2 * tp + r) * 65 + cic * 8 + c];
#pragma unroll
    for (int n = 0; n < 16; n++) {
      const float* wr = w2 + (cq * 16 + n) * 192 + cic * 24;  // native [co][ci][kk]
#pragma unroll
      for (int c = 0; c < 8; c++) {
#pragma unroll
        for (int kk = 0; kk < 3; kk++) {
          float w = wr[c * 3 + kk];
          acc0[n] = fmaf(p[kk][c],     w, acc0[n]);
          acc1[n] = fmaf(p[kk + 1][c], w, acc1[n]);
        }
      }
    }
  }
  __syncthreads();                               // reuse xs as [tp][co]
#pragma unroll
  for (int n = 0; n < 16; n += 4) {
    float4 v;
    v.x = fmaxf(fmaxf(acc0[n],     acc1[n]),     0.f);
    v.y = fmaxf(fmaxf(acc0[n + 1], acc1[n + 1]), 0.f);
    v.z = fmaxf(fmaxf(acc0[n + 2], acc1[n + 2]), 0.f);
    v.w = fmaxf(fmaxf(acc0[n + 3], acc1[n + 3]), 0.f);
    *(float4*)&xs[tp * 128 + cq * 16 + n] = v;
  }
  __syncthreads();
  float* fb = feats + (size_t)b * 8192;
  for (int idx = tid; idx < 8192; idx += 512) fb[idx] = xs[idx];
}

// --------------------------- LTC recurrence + head -------------------------
// block = 1024 threads: j = tid&127 (unit), h = tid>>7 (i-octant).
// 2 batches/block, grid 256 = 1 block/CU. (r1,r2) in LDS; vw in 16 VGPRs;
// sensory S2/SV streamed from L2. h==0-only reduce (R10 form — replicated
// reduce state spills, see R12).
__launch_bounds__(1024)
__global__ void lnn_kernel(const float2* __restrict__ R12, const float* __restrict__ VT,
                           const float2* __restrict__ S2,  const float* __restrict__ SV,
                           const float* __restrict__ feats,
                           const float* __restrict__ cm_t, const float* __restrict__ gleak,
                           const float* __restrict__ vleak,
                           const float* __restrict__ fc1_w, const float* __restrict__ fc1_b,
                           const float* __restrict__ fc2_w, const float* __restrict__ fc2_b,
                           float* __restrict__ out) {
  __shared__ float2 r12lds[16384];               // 128KB: (r1, r2)[i][j]
  __shared__ float4 psum[8][128];                // 16KB
  __shared__ float2 vs2[128];
  __shared__ float2 xt2[128];
  __shared__ float red[2][64];
  int tid = threadIdx.x;
  int j = tid & 127, h = tid >> 7;               // h in [0,8)
  int b0 = blockIdx.x * 2;

  // stage (r1,r2) table into LDS (16 coalesced float2 iters)
  for (int idx = tid; idx < 16384; idx += 1024) r12lds[idx] = R12[idx];

  // vw -> VGPRs (16 regs; coalesced over j)
  float vw[16];
#pragma unroll
  for (int n = 0; n < 16; n++) vw[n] = VT[(16 * h + n) * 128 + j];

  float cmj = cm_t[j], glk = gleak[j];
  float gvl = glk * vleak[j], cgl = cmj + glk;
  float vj0 = 0.f, vj1 = 0.f;
  if (tid < 128) vs2[j] = make_float2(0.f, 0.f);
  __syncthreads();

  for (int t = 0; t < 64; t++) {
    // stage raw features for both batches (affine folded into S2 tables)
    if (tid < 128) {
      float a = feats[(size_t)b0 * 8192 + t * 128 + j];
      float b = feats[(size_t)(b0 + 1) * 8192 + t * 128 + j];
      xt2[j] = make_float2(a, b);
    }
    __syncthreads();

    // ---- sensory partials (S2 + SV streamed from L2) ----
    float sn0 = 0.f, sd0 = 0.f, sn1 = 0.f, sd1 = 0.f;
    {
      float n0 = 0.f, d0 = 0.f, n1 = 0.f, d1 = 0.f;
      const float2* sp = S2 + (size_t)(16 * h) * 128 + j;
      const float*  vp = SV + (size_t)(16 * h) * 128 + j;
#pragma unroll
      for (int n = 0; n < 16; n++) {
        float2 s = sp[n * 128];
        float svv = vp[n * 128];
        float2 xv = xt2[16 * h + n];
        float q0 = __builtin_amdgcn_rcpf(1.f + __builtin_amdgcn_exp2f(fmaf(-s.x, xv.x, s.y)));
        n0 = fmaf(svv, q0, n0); d0 = fmaf(fabsf(svv), q0, d0);
        float q1 = __builtin_amdgcn_rcpf(1.f + __builtin_amdgcn_exp2f(fmaf(-s.x, xv.y, s.y)));
        n1 = fmaf(svv, q1, n1); d1 = fmaf(fabsf(svv), q1, d1);
      }
      psum[h][j] = make_float4(n0, d0, n1, d1);
    }
    __syncthreads();
    if (h == 0) {                                // wave-uniform branch
      float4 a0 = psum[0][j], a1 = psum[1][j], a2 = psum[2][j], a3 = psum[3][j];
      float4 a4 = psum[4][j], a5 = psum[5][j], a6 = psum[6][j], a7 = psum[7][j];
      sn0 = a0.x + a1.x + a2.x + a3.x + a4.x + a5.x + a6.x + a7.x;
      sd0 = a0.y + a1.y + a2.y + a3.y + a4.y + a5.y + a6.y + a7.y;
      sn1 = a0.z + a1.z + a2.z + a3.z + a4.z + a5.z + a6.z + a7.z;
      sd1 = a0.w + a1.w + a2.w + a3.w + a4.w + a5.w + a6.w + a7.w;
    }
    __syncthreads();                             // psum reusable after this

    // ---- 6 semi-implicit ODE unfolds ((r1,r2) from LDS, vw in VGPRs) ----
    for (int u = 0; u < 6; u++) {
      float n0 = 0.f, d0 = 0.f, n1 = 0.f, d1 = 0.f;
      const float2* mp = &r12lds[(16 * h) * 128 + j];
#pragma unroll
      for (int n = 0; n < 16; n++) {
        float2 rr = mp[n * 128];                 // stride-8B b64, conflict-free
        float2 v2 = vs2[16 * h + n];             // broadcast read
        float q0 = __builtin_amdgcn_rcpf(1.f + __builtin_amdgcn_exp2f(fmaf(-rr.x, v2.x, rr.y)));
        n0 = fmaf(vw[n], q0, n0); d0 = fmaf(fabsf(vw[n]), q0, d0);
        float q1 = __builtin_amdgcn_rcpf(1.f + __builtin_amdgcn_exp2f(fmaf(-rr.x, v2.y, rr.y)));
        n1 = fmaf(vw[n], q1, n1); d1 = fmaf(fabsf(vw[n]), q1, d1);
      }
      psum[h][j] = make_float4(n0, d0, n1, d1);
      __syncthreads();
      if (h == 0) {                              // wave-uniform
        float4 a0 = psum[0][j], a1 = psum[1][j], a2 = psum[2][j], a3 = psum[3][j];
        float4 a4 = psum[4][j], a5 = psum[5][j], a6 = psum[6][j], a7 = psum[7][j];
        float wn0 = sn0 + a0.x + a1.x + a2.x + a3.x + a4.x + a5.x + a6.x + a7.x;
        float wd0 = sd0 + a0.y + a1.y + a2.y + a3.y + a4.y + a5.y + a6.y + a7.y;
        float wn1 = sn1 + a0.z + a1.z + a2.z + a3.z + a4.z + a5.z + a6.z + a7.z;
        float wd1 = sd1 + a0.w + a1.w + a2.w + a3.w + a4.w + a5.w + a6.w + a7.w;
        // NR-refined rcp (den > 1.5 always; ~1ulp vs IEEE div)
        float den0 = cgl + wd0, den1 = cgl + wd1;
        float i0 = __builtin_amdgcn_rcpf(den0); i0 = i0 * fmaf(-den0, i0, 2.f);
        float i1 = __builtin_amdgcn_rcpf(den1); i1 = i1 * fmaf(-den1, i1, 2.f);
        vj0 = (fmaf(cmj, vj0, gvl) + wn0) * i0;
        vj1 = (fmaf(cmj, vj1, gvl) + wn1) * i1;
        vs2[j] = make_float2(vj0, vj1);
      }
      __syncthreads();
    }
  }

  // ---- MLP head (naive pattern: LDS red + sequential final sum) ----
  if (tid < 128) {
    int g = tid >> 6, d = tid & 63;
    float acc = fc1_b[d];
    for (int u = 0; u < 128; u++) {
      float2 v2 = vs2[u];
      acc = fmaf(g ? v2.y : v2.x, fc1_w[d * 128 + u], acc);
    }
    red[g][d] = fmaxf(acc, 0.f) * fc2_w[d];
  }
  __syncthreads();
  if (tid < 2) {
    float s = fc2_b[0];
    for (int d = 0; d < 64; d++) s += red[tid][d];
    out[b0 + tid] = s;
  }
}

// ------------------------------- launcher ----------------------------------
extern "C" void kernel_launch(void* const* d_in, const int* in_sizes, int n_in,
                              void* d_out, int out_size, void* d_ws, size_t ws_size,
                              hipStream_t stream) {
  (void)in_sizes; (void)n_in; (void)out_size; (void)ws_size;
  char* ws = (char*)d_ws;
  // Proven 32MB envelope, time-multiplexed:
  //   P1 [0,16M) live conv1->conv2; tables [0,384K) after conv2 (prep);
  //   feats [16M,32M) live conv2->lnn.
  float*  P1   = (float*)(ws);
  float*  feats= (float*)(ws + (16 << 20));
  float2* R12  = (float2*)(ws + 0);             // 128KB
  float*  VT   = (float*)(ws + (128 << 10));    // 64KB
  float2* S2   = (float2*)(ws + (192 << 10));   // 128KB
  float*  SV   = (float*)(ws + (320 << 10));    // 64KB -> ends 384KB

  conv1_kernel<<<512, 512, 0, stream>>>((const float*)d_in[0],
      (const float*)d_in[1], (const float*)d_in[2], P1);
  conv2_kernel<<<512, 512, 0, stream>>>(P1,
      (const float*)d_in[3], (const float*)d_in[4], feats);
  prep_kernel<<<64, 256, 0, stream>>>(
      (const float*)d_in[7], (const float*)d_in[8],
      (const float*)d_in[9], (const float*)d_in[10],
      (const float*)d_in[11], (const float*)d_in[12],
      (const float*)d_in[13], (const float*)d_in[14],
      (const float*)d_in[5], (const float*)d_in[6],
      R12, VT, S2, SV);
  lnn_kernel<<<256, 1024, 0, stream>>>(R12, VT, S2, SV, feats,
      (const float*)d_in[17], (const float*)d_in[16], (const float*)d_in[15],
      (const float*)d_in[18], (const float*)d_in[19],
      (const float*)d_in[20], (const float*)d_in[21],
      (float*)d_out);
}

// Round 14
// 1350.288 us; speedup vs baseline: 1.5525x; 1.0367x over previous
//
#include <hip/hip_runtime.h>
#include <hip/hip_bf16.h>

// ---------------------------------------------------------------------------
// HybridCnnLnn R14 = R13 + #pragma unroll 8 on the two hot lnn loops.
// R13 post-mortem: fma-fold cut busy 888->738us, but full 16-deep unroll
// hoists 48 regs of in-flight loads -> crosses the immovable 64-VGPR budget
// -> 258MB scratch FETCH (R12's spill was THIS, not the replicated reduce).
// unroll 8 halves in-flight loads; loop overhead is noise vs 16cy/cell trans.
// Toxic list: ext-vector v2f (R11), replicated reduce state (R12),
// full-unroll load hoisting (R13). Trans floor 382us busy.
// ---------------------------------------------------------------------------

#define L2E 1.4426950408889634f

// ---------------- prep: fold params, native [i][j] layout (identity) -------
__global__ __launch_bounds__(256)
void prep_kernel(const float* __restrict__ smu, const float* __restrict__ ssig,
                 const float* __restrict__ sW,  const float* __restrict__ serev,
                 const float* __restrict__ mu,  const float* __restrict__ sig,
                 const float* __restrict__ W,   const float* __restrict__ erev,
                 const float* __restrict__ in_w, const float* __restrict__ in_b,
                 float2* __restrict__ R12, float* __restrict__ VT,
                 float2* __restrict__ S2,  float* __restrict__ SV) {
  int idx = blockIdx.x * 256 + threadIdx.x;      // 64 blocks x 256 = 16384
  int i = idx >> 7;
  float r1 = sig[idx] * L2E;
  R12[idx] = make_float2(r1, mu[idx] * r1);      // z = r2 - r1*v
  VT[idx]  = W[idx] * erev[idx];                 // |erev|=1 -> |VT| = W
  float ss = ssig[idx] * L2E;
  S2[idx]  = make_float2(ss * in_w[i], (smu[idx] - in_b[i]) * ss);  // z = s2 - s1*f
  SV[idx]  = sW[idx] * serev[idx];
}

// ----------------------------- conv1 (k=5, tiled) --------------------------
// x [512,256,24] -> P1 [512,64,128] ([b][co][t']), relu+maxpool2 fused
__launch_bounds__(512)
__global__ void conv1_kernel(const float* __restrict__ x, const float* __restrict__ w1,
                             const float* __restrict__ b1, float* __restrict__ P1) {
  __shared__ float xs[6240];                     // rows t in [-2,258), 24 ch
  int tid = threadIdx.x, b = blockIdx.x;
  const float* xb = x + (size_t)b * 6144;
  for (int idx = tid; idx < 6144; idx += 512) xs[idx + 48] = xb[idx];
  if (tid < 48) { xs[tid] = 0.f; xs[6192 + tid] = 0.f; }
  __syncthreads();
  int tp = tid & 127, cq = tid >> 7;             // 128 pooled t x 4 co-quarters
  float acc0[16], acc1[16];
#pragma unroll
  for (int n = 0; n < 16; n++) { float bb = b1[cq * 16 + n]; acc0[n] = bb; acc1[n] = bb; }
  for (int cic = 0; cic < 3; cic++) {            // ci chunks of 8
    float p[6][8];
#pragma unroll
    for (int r = 0; r < 6; r++) {
      const float* row = &xs[(2 * tp + r) * 24 + cic * 8];
      float4 a = *(const float4*)row;
      float4 c = *(const float4*)(row + 4);
      p[r][0] = a.x; p[r][1] = a.y; p[r][2] = a.z; p[r][3] = a.w;
      p[r][4] = c.x; p[r][5] = c.y; p[r][6] = c.z; p[r][7] = c.w;
    }
#pragma unroll
    for (int n = 0; n < 16; n++) {
      const float* wr = w1 + (cq * 16 + n) * 120 + cic * 40;  // uniform -> s_load
#pragma unroll
      for (int c = 0; c < 8; c++) {
#pragma unroll
        for (int kk = 0; kk < 5; kk++) {
          float w = wr[c * 5 + kk];
          acc0[n] = fmaf(p[kk][c],     w, acc0[n]);
          acc1[n] = fmaf(p[kk + 1][c], w, acc1[n]);
        }
      }
    }
  }
  float* pb = P1 + (size_t)b * 8192;
#pragma unroll
  for (int n = 0; n < 16; n++)
    pb[(cq * 16 + n) * 128 + tp] = fmaxf(fmaxf(acc0[n], acc1[n]), 0.f);
}

// ----------------------------- conv2 (k=3, tiled) --------------------------
// P1 [512,64,128] -> feats [512,64,128] laid out [b][t'][co]
__launch_bounds__(512)
__global__ void conv2_kernel(const float* __restrict__ P1, const float* __restrict__ w2,
                             const float* __restrict__ b2, float* __restrict__ feats) {
  __shared__ float xs[8450];                     // [t+1][ci], stride 65
  int tid = threadIdx.x, b = blockIdx.x;
  const float* pb = P1 + (size_t)b * 8192;
  for (int idx = tid; idx < 8192; idx += 512) {
    int ci = idx >> 7, t = idx & 127;
    xs[(t + 1) * 65 + ci] = pb[idx];
  }
  if (tid < 65) { xs[tid] = 0.f; xs[129 * 65 + tid] = 0.f; }
  __syncthreads();
  int tp = tid & 63, cq = tid >> 6;              // 64 pooled t x 8 co-octants
  float acc0[16], acc1[16];
#pragma unroll
  for (int n = 0; n < 16; n++) { float bb = b2[cq * 16 + n]; acc0[n] = bb; acc1[n] = bb; }
  for (int cic = 0; cic < 8; cic++) {            // ci chunks of 8
    float p[4][8];
#pragma unroll
    for (int r = 0; r < 4; r++)
#pragma unroll
      for (int c = 0; c < 8; c++)
        p[r][c] = xs[(2 * tp + r) * 65 + cic * 8 + c];
#pragma unroll
    for (int n = 0; n < 16; n++) {
      const float* wr = w2 + (cq * 16 + n) * 192 + cic * 24;  // native [co][ci][kk]
#pragma unroll
      for (int c = 0; c < 8; c++) {
#pragma unroll
        for (int kk = 0; kk < 3; kk++) {
          float w = wr[c * 3 + kk];
          acc0[n] = fmaf(p[kk][c],     w, acc0[n]);
          acc1[n] = fmaf(p[kk + 1][c], w, acc1[n]);
        }
      }
    }
  }
  __syncthreads();                               // reuse xs as [tp][co]
#pragma unroll
  for (int n = 0; n < 16; n += 4) {
    float4 v;
    v.x = fmaxf(fmaxf(acc0[n],     acc1[n]),     0.f);
    v.y = fmaxf(fmaxf(acc0[n + 1], acc1[n + 1]), 0.f);
    v.z = fmaxf(fmaxf(acc0[n + 2], acc1[n + 2]), 0.f);
    v.w = fmaxf(fmaxf(acc0[n + 3], acc1[n + 3]), 0.f);
    *(float4*)&xs[tp * 128 + cq * 16 + n] = v;
  }
  __syncthreads();
  float* fb = feats + (size_t)b * 8192;
  for (int idx = tid; idx < 8192; idx += 512) fb[idx] = xs[idx];
}

// --------------------------- LTC recurrence + head -------------------------
// block = 1024 threads: j = tid&127 (unit), h = tid>>7 (i-octant).
// 2 batches/block, grid 256 = 1 block/CU. (r1,r2) in LDS; vw in 16 VGPRs;
// sensory S2/SV streamed from L2. h==0-only reduce. unroll 8 (not 16!) on
// hot loops to keep in-flight loads under the 64-VGPR budget.
__launch_bounds__(1024)
__global__ void lnn_kernel(const float2* __restrict__ R12, const float* __restrict__ VT,
                           const float2* __restrict__ S2,  const float* __restrict__ SV,
                           const float* __restrict__ feats,
                           const float* __restrict__ cm_t, const float* __restrict__ gleak,
                           const float* __restrict__ vleak,
                           const float* __restrict__ fc1_w, const float* __restrict__ fc1_b,
                           const float* __restrict__ fc2_w, const float* __restrict__ fc2_b,
                           float* __restrict__ out) {
  __shared__ float2 r12lds[16384];               // 128KB: (r1, r2)[i][j]
  __shared__ float4 psum[8][128];                // 16KB
  __shared__ float2 vs2[128];
  __shared__ float2 xt2[128];
  __shared__ float red[2][64];
  int tid = threadIdx.x;
  int j = tid & 127, h = tid >> 7;               // h in [0,8)
  int b0 = blockIdx.x * 2;

  // stage (r1,r2) table into LDS (16 coalesced float2 iters)
  for (int idx = tid; idx < 16384; idx += 1024) r12lds[idx] = R12[idx];

  // vw -> VGPRs (16 regs; coalesced over j)
  float vw[16];
#pragma unroll
  for (int n = 0; n < 16; n++) vw[n] = VT[(16 * h + n) * 128 + j];

  float cmj = cm_t[j], glk = gleak[j];
  float gvl = glk * vleak[j], cgl = cmj + glk;
  float vj0 = 0.f, vj1 = 0.f;
  if (tid < 128) vs2[j] = make_float2(0.f, 0.f);
  __syncthreads();

  for (int t = 0; t < 64; t++) {
    // stage raw features for both batches (affine folded into S2 tables)
    if (tid < 128) {
      float a = feats[(size_t)b0 * 8192 + t * 128 + j];
      float b = feats[(size_t)(b0 + 1) * 8192 + t * 128 + j];
      xt2[j] = make_float2(a, b);
    }
    __syncthreads();

    // ---- sensory partials (S2 + SV streamed from L2) ----
    float sn0 = 0.f, sd0 = 0.f, sn1 = 0.f, sd1 = 0.f;
    {
      float n0 = 0.f, d0 = 0.f, n1 = 0.f, d1 = 0.f;
      const float2* sp = S2 + (size_t)(16 * h) * 128 + j;
      const float*  vp = SV + (size_t)(16 * h) * 128 + j;
#pragma unroll 8
      for (int n = 0; n < 16; n++) {
        float2 s = sp[n * 128];
        float svv = vp[n * 128];
        float2 xv = xt2[16 * h + n];
        float q0 = __builtin_amdgcn_rcpf(1.f + __builtin_amdgcn_exp2f(fmaf(-s.x, xv.x, s.y)));
        n0 = fmaf(svv, q0, n0); d0 = fmaf(fabsf(svv), q0, d0);
        float q1 = __builtin_amdgcn_rcpf(1.f + __builtin_amdgcn_exp2f(fmaf(-s.x, xv.y, s.y)));
        n1 = fmaf(svv, q1, n1); d1 = fmaf(fabsf(svv), q1, d1);
      }
      psum[h][j] = make_float4(n0, d0, n1, d1);
    }
    __syncthreads();
    if (h == 0) {                                // wave-uniform branch
      float4 a0 = psum[0][j], a1 = psum[1][j], a2 = psum[2][j], a3 = psum[3][j];
      float4 a4 = psum[4][j], a5 = psum[5][j], a6 = psum[6][j], a7 = psum[7][j];
      sn0 = a0.x + a1.x + a2.x + a3.x + a4.x + a5.x + a6.x + a7.x;
      sd0 = a0.y + a1.y + a2.y + a3.y + a4.y + a5.y + a6.y + a7.y;
      sn1 = a0.z + a1.z + a2.z + a3.z + a4.z + a5.z + a6.z + a7.z;
      sd1 = a0.w + a1.w + a2.w + a3.w + a4.w + a5.w + a6.w + a7.w;
    }
    __syncthreads();                             // psum reusable after this

    // ---- 6 semi-implicit ODE unfolds ((r1,r2) from LDS, vw in VGPRs) ----
    for (int u = 0; u < 6; u++) {
      float n0 = 0.f, d0 = 0.f, n1 = 0.f, d1 = 0.f;
      const float2* mp = &r12lds[(16 * h) * 128 + j];
#pragma unroll 8
      for (int n = 0; n < 16; n++) {
        float2 rr = mp[n * 128];                 // stride-8B b64, conflict-free
        float2 v2 = vs2[16 * h + n];             // broadcast read
        float q0 = __builtin_amdgcn_rcpf(1.f + __builtin_amdgcn_exp2f(fmaf(-rr.x, v2.x, rr.y)));
        n0 = fmaf(vw[n], q0, n0); d0 = fmaf(fabsf(vw[n]), q0, d0);
        float q1 = __builtin_amdgcn_rcpf(1.f + __builtin_amdgcn_exp2f(fmaf(-rr.x, v2.y, rr.y)));
        n1 = fmaf(vw[n], q1, n1); d1 = fmaf(fabsf(vw[n]), q1, d1);
      }
      psum[h][j] = make_float4(n0, d0, n1, d1);
      __syncthreads();
      if (h == 0) {                              // wave-uniform
        float4 a0 = psum[0][j], a1 = psum[1][j], a2 = psum[2][j], a3 = psum[3][j];
        float4 a4 = psum[4][j], a5 = psum[5][j], a6 = psum[6][j], a7 = psum[7][j];
        float wn0 = sn0 + a0.x + a1.x + a2.x + a3.x + a4.x + a5.x + a6.x + a7.x;
        float wd0 = sd0 + a0.y + a1.y + a2.y + a3.y + a4.y + a5.y + a6.y + a7.y;
        float wn1 = sn1 + a0.z + a1.z + a2.z + a3.z + a4.z + a5.z + a6.z + a7.z;
        float wd1 = sd1 + a0.w + a1.w + a2.w + a3.w + a4.w + a5.w + a6.w + a7.w;
        // NR-refined rcp (den > 1.5 always; ~1ulp vs IEEE div)
        float den0 = cgl + wd0, den1 = cgl + wd1;
        float i0 = __builtin_amdgcn_rcpf(den0); i0 = i0 * fmaf(-den0, i0, 2.f);
        float i1 = __builtin_amdgcn_rcpf(den1); i1 = i1 * fmaf(-den1, i1, 2.f);
        vj0 = (fmaf(cmj, vj0, gvl) + wn0) * i0;
        vj1 = (fmaf(cmj, vj1, gvl) + wn1) * i1;
        vs2[j] = make_float2(vj0, vj1);
      }
      __syncthreads();
    }
  }

  // ---- MLP head (naive pattern: LDS red + sequential final sum) ----
  if (tid < 128) {
    int g = tid >> 6, d = tid & 63;
    float acc = fc1_b[d];
    for (int u = 0; u < 128; u++) {
      float2 v2 = vs2[u];
      acc = fmaf(g ? v2.y : v2.x, fc1_w[d * 128 + u], acc);
    }
    red[g][d] = fmaxf(acc, 0.f) * fc2_w[d];
  }
  __syncthreads();
  if (tid < 2) {
    float s = fc2_b[0];
    for (int d = 0; d < 64; d++) s += red[tid][d];
    out[b0 + tid] = s;
  }
}

// ------------------------------- launcher ----------------------------------
extern "C" void kernel_launch(void* const* d_in, const int* in_sizes, int n_in,
                              void* d_out, int out_size, void* d_ws, size_t ws_size,
                              hipStream_t stream) {
  (void)in_sizes; (void)n_in; (void)out_size; (void)ws_size;
  char* ws = (char*)d_ws;
  // Proven 32MB envelope, time-multiplexed:
  //   P1 [0,16M) live conv1->conv2; tables [0,384K) after conv2 (prep);
  //   feats [16M,32M) live conv2->lnn.
  float*  P1   = (float*)(ws);
  float*  feats= (float*)(ws + (16 << 20));
  float2* R12  = (float2*)(ws + 0);             // 128KB
  float*  VT   = (float*)(ws + (128 << 10));    // 64KB
  float2* S2   = (float2*)(ws + (192 << 10));   // 128KB
  float*  SV   = (float*)(ws + (320 << 10));    // 64KB -> ends 384KB

  conv1_kernel<<<512, 512, 0, stream>>>((const float*)d_in[0],
      (const float*)d_in[1], (const float*)d_in[2], P1);
  conv2_kernel<<<512, 512, 0, stream>>>(P1,
      (const float*)d_in[3], (const float*)d_in[4], feats);
  prep_kernel<<<64, 256, 0, stream>>>(
      (const float*)d_in[7], (const float*)d_in[8],
      (const float*)d_in[9], (const float*)d_in[10],
      (const float*)d_in[11], (const float*)d_in[12],
      (const float*)d_in[13], (const float*)d_in[14],
      (const float*)d_in[5], (const float*)d_in[6],
      R12, VT, S2, SV);
  lnn_kernel<<<256, 1024, 0, stream>>>(R12, VT, S2, SV, feats,
      (const float*)d_in[17], (const float*)d_in[16], (const float*)d_in[15],
      (const float*)d_in[18], (const float*)d_in[19],
      (const float*)d_in[20], (const float*)d_in[21],
      (float*)d_out);
}

// Round 15
// 1228.744 us; speedup vs baseline: 1.7060x; 1.0989x over previous
//
#include <hip/hip_runtime.h>
#include <hip/hip_bf16.h>

// ---------------------------------------------------------------------------
// HybridCnnLnn R15: asymmetric unroll, informed by the R10..R14 ledger:
//  - R10 (full unroll both, sub-mul): 1153us, busy 888, NO spill
//  - R13 (full unroll both, fold):    spill (global-load hoisting explosion)
//  - R14 (unroll 8 both, fold):       1200us, busy 911 (loop overhead ate fold)
// => unfold loop (LDS-only, 6/7 of work): FULL unroll + fold (R10-proven shape)
//    sensory loop (global streams): unroll 8 + fold + packed float4 table
//    (1 b128 load/iter instead of b64+b32) to cap VMEM in flight.
// NR rcp in serial section. Arithmetic identical to R14 -> absmax 0.0.
// Spill tripwire: FETCH>50MB -> revert unfold to unroll 8.
// ---------------------------------------------------------------------------

#define L2E 1.4426950408889634f

// ---------------- prep: fold params, native [i][j] layout (identity) -------
__global__ __launch_bounds__(256)
void prep_kernel(const float* __restrict__ smu, const float* __restrict__ ssig,
                 const float* __restrict__ sW,  const float* __restrict__ serev,
                 const float* __restrict__ mu,  const float* __restrict__ sig,
                 const float* __restrict__ W,   const float* __restrict__ erev,
                 const float* __restrict__ in_w, const float* __restrict__ in_b,
                 float2* __restrict__ R12, float* __restrict__ VT,
                 float4* __restrict__ S4) {
  int idx = blockIdx.x * 256 + threadIdx.x;      // 64 blocks x 256 = 16384
  int i = idx >> 7;
  float r1 = sig[idx] * L2E;
  R12[idx] = make_float2(r1, mu[idx] * r1);      // z = r2 - r1*v
  VT[idx]  = W[idx] * erev[idx];                 // |erev|=1 -> |VT| = W
  float ss = ssig[idx] * L2E;
  // sensory: z = s2 - s1*f (in_w/in_b folded); sv = sW*serev; one b128 load
  S4[idx] = make_float4(ss * in_w[i], (smu[idx] - in_b[i]) * ss,
                        sW[idx] * serev[idx], 0.f);
}

// ----------------------------- conv1 (k=5, tiled) --------------------------
// x [512,256,24] -> P1 [512,64,128] ([b][co][t']), relu+maxpool2 fused
__launch_bounds__(512)
__global__ void conv1_kernel(const float* __restrict__ x, const float* __restrict__ w1,
                             const float* __restrict__ b1, float* __restrict__ P1) {
  __shared__ float xs[6240];                     // rows t in [-2,258), 24 ch
  int tid = threadIdx.x, b = blockIdx.x;
  const float* xb = x + (size_t)b * 6144;
  for (int idx = tid; idx < 6144; idx += 512) xs[idx + 48] = xb[idx];
  if (tid < 48) { xs[tid] = 0.f; xs[6192 + tid] = 0.f; }
  __syncthreads();
  int tp = tid & 127, cq = tid >> 7;             // 128 pooled t x 4 co-quarters
  float acc0[16], acc1[16];
#pragma unroll
  for (int n = 0; n < 16; n++) { float bb = b1[cq * 16 + n]; acc0[n] = bb; acc1[n] = bb; }
  for (int cic = 0; cic < 3; cic++) {            // ci chunks of 8
    float p[6][8];
#pragma unroll
    for (int r = 0; r < 6; r++) {
      const float* row = &xs[(2 * tp + r) * 24 + cic * 8];
      float4 a = *(const float4*)row;
      float4 c = *(const float4*)(row + 4);
      p[r][0] = a.x; p[r][1] = a.y; p[r][2] = a.z; p[r][3] = a.w;
      p[r][4] = c.x; p[r][5] = c.y; p[r][6] = c.z; p[r][7] = c.w;
    }
#pragma unroll
    for (int n = 0; n < 16; n++) {
      const float* wr = w1 + (cq * 16 + n) * 120 + cic * 40;  // uniform -> s_load
#pragma unroll
      for (int c = 0; c < 8; c++) {
#pragma unroll
        for (int kk = 0; kk < 5; kk++) {
          float w = wr[c * 5 + kk];
          acc0[n] = fmaf(p[kk][c],     w, acc0[n]);
          acc1[n] = fmaf(p[kk + 1][c], w, acc1[n]);
        }
      }
    }
  }
  float* pb = P1 + (size_t)b * 8192;
#pragma unroll
  for (int n = 0; n < 16; n++)
    pb[(cq * 16 + n) * 128 + tp] = fmaxf(fmaxf(acc0[n], acc1[n]), 0.f);
}

// ----------------------------- conv2 (k=3, tiled) --------------------------
// P1 [512,64,128] -> feats [512,64,128] laid out [b][t'][co]
__launch_bounds__(512)
__global__ void conv2_kernel(const float* __restrict__ P1, const float* __restrict__ w2,
                             const float* __restrict__ b2, float* __restrict__ feats) {
  __shared__ float xs[8450];                     // [t+1][ci], stride 65
  int tid = threadIdx.x, b = blockIdx.x;
  const float* pb = P1 + (size_t)b * 8192;
  for (int idx = tid; idx < 8192; idx += 512) {
    int ci = idx >> 7, t = idx & 127;
    xs[(t + 1) * 65 + ci] = pb[idx];
  }
  if (tid < 65) { xs[tid] = 0.f; xs[129 * 65 + tid] = 0.f; }
  __syncthreads();
  int tp = tid & 63, cq = tid >> 6;              // 64 pooled t x 8 co-octants
  float acc0[16], acc1[16];
#pragma unroll
  for (int n = 0; n < 16; n++) { float bb = b2[cq * 16 + n]; acc0[n] = bb; acc1[n] = bb; }
  for (int cic = 0; cic < 8; cic++) {            // ci chunks of 8
    float p[4][8];
#pragma unroll
    for (int r = 0; r < 4; r++)
#pragma unroll
      for (int c = 0; c < 8; c++)
        p[r][c] = xs[(2 * tp + r) * 65 + cic * 8 + c];
#pragma unroll
    for (int n = 0; n < 16; n++) {
      const float* wr = w2 + (cq * 16 + n) * 192 + cic * 24;  // native [co][ci][kk]
#pragma unroll
      for (int c = 0; c < 8; c++) {
#pragma unroll
        for (int kk = 0; kk < 3; kk++) {
          float w = wr[c * 3 + kk];
          acc0[n] = fmaf(p[kk][c],     w, acc0[n]);
          acc1[n] = fmaf(p[kk + 1][c], w, acc1[n]);
        }
      }
    }
  }
  __syncthreads();                               // reuse xs as [tp][co]
#pragma unroll
  for (int n = 0; n < 16; n += 4) {
    float4 v;
    v.x = fmaxf(fmaxf(acc0[n],     acc1[n]),     0.f);
    v.y = fmaxf(fmaxf(acc0[n + 1], acc1[n + 1]), 0.f);
    v.z = fmaxf(fmaxf(acc0[n + 2], acc1[n + 2]), 0.f);
    v.w = fmaxf(fmaxf(acc0[n + 3], acc1[n + 3]), 0.f);
    *(float4*)&xs[tp * 128 + cq * 16 + n] = v;
  }
  __syncthreads();
  float* fb = feats + (size_t)b * 8192;
  for (int idx = tid; idx < 8192; idx += 512) fb[idx] = xs[idx];
}

// --------------------------- LTC recurrence + head -------------------------
// block = 1024 threads: j = tid&127 (unit), h = tid>>7 (i-octant).
// 2 batches/block, grid 256 = 1 block/CU. (r1,r2) in LDS; vw in 16 VGPRs;
// sensory S4 streamed from L2 (unroll 8, b128). Unfold loop: FULL unroll
// (LDS-only — R10-proven spill-free shape). h==0-only reduce.
__launch_bounds__(1024)
__global__ void lnn_kernel(const float2* __restrict__ R12, const float* __restrict__ VT,
                           const float4* __restrict__ S4,
                           const float* __restrict__ feats,
                           const float* __restrict__ cm_t, const float* __restrict__ gleak,
                           const float* __restrict__ vleak,
                           const float* __restrict__ fc1_w, const float* __restrict__ fc1_b,
                           const float* __restrict__ fc2_w, const float* __restrict__ fc2_b,
                           float* __restrict__ out) {
  __shared__ float2 r12lds[16384];               // 128KB: (r1, r2)[i][j]
  __shared__ float4 psum[8][128];                // 16KB
  __shared__ float2 vs2[128];
  __shared__ float2 xt2[128];
  __shared__ float red[2][64];
  int tid = threadIdx.x;
  int j = tid & 127, h = tid >> 7;               // h in [0,8)
  int b0 = blockIdx.x * 2;

  // stage (r1,r2) table into LDS (16 coalesced float2 iters)
  for (int idx = tid; idx < 16384; idx += 1024) r12lds[idx] = R12[idx];

  // vw -> VGPRs (16 regs; coalesced over j)
  float vw[16];
#pragma unroll
  for (int n = 0; n < 16; n++) vw[n] = VT[(16 * h + n) * 128 + j];

  float cmj = cm_t[j], glk = gleak[j];
  float gvl = glk * vleak[j], cgl = cmj + glk;
  float vj0 = 0.f, vj1 = 0.f;
  if (tid < 128) vs2[j] = make_float2(0.f, 0.f);
  __syncthreads();

  for (int t = 0; t < 64; t++) {
    // stage raw features for both batches (affine folded into S4 table)
    if (tid < 128) {
      float a = feats[(size_t)b0 * 8192 + t * 128 + j];
      float b = feats[(size_t)(b0 + 1) * 8192 + t * 128 + j];
      xt2[j] = make_float2(a, b);
    }
    __syncthreads();

    // ---- sensory partials (packed S4 streamed from L2; unroll 8) ----
    float sn0 = 0.f, sd0 = 0.f, sn1 = 0.f, sd1 = 0.f;
    {
      float n0 = 0.f, d0 = 0.f, n1 = 0.f, d1 = 0.f;
      const float4* sp = S4 + (size_t)(16 * h) * 128 + j;
#pragma unroll 8
      for (int n = 0; n < 16; n++) {
        float4 s = sp[n * 128];
        float2 xv = xt2[16 * h + n];
        float q0 = __builtin_amdgcn_rcpf(1.f + __builtin_amdgcn_exp2f(fmaf(-s.x, xv.x, s.y)));
        n0 = fmaf(s.z, q0, n0); d0 = fmaf(fabsf(s.z), q0, d0);
        float q1 = __builtin_amdgcn_rcpf(1.f + __builtin_amdgcn_exp2f(fmaf(-s.x, xv.y, s.y)));
        n1 = fmaf(s.z, q1, n1); d1 = fmaf(fabsf(s.z), q1, d1);
      }
      psum[h][j] = make_float4(n0, d0, n1, d1);
    }
    __syncthreads();
    if (h == 0) {                                // wave-uniform branch
      float4 a0 = psum[0][j], a1 = psum[1][j], a2 = psum[2][j], a3 = psum[3][j];
      float4 a4 = psum[4][j], a5 = psum[5][j], a6 = psum[6][j], a7 = psum[7][j];
      sn0 = a0.x + a1.x + a2.x + a3.x + a4.x + a5.x + a6.x + a7.x;
      sd0 = a0.y + a1.y + a2.y + a3.y + a4.y + a5.y + a6.y + a7.y;
      sn1 = a0.z + a1.z + a2.z + a3.z + a4.z + a5.z + a6.z + a7.z;
      sd1 = a0.w + a1.w + a2.w + a3.w + a4.w + a5.w + a6.w + a7.w;
    }
    __syncthreads();                             // psum reusable after this

    // ---- 6 semi-implicit ODE unfolds ((r1,r2) from LDS; FULL unroll) ----
    for (int u = 0; u < 6; u++) {
      float n0 = 0.f, d0 = 0.f, n1 = 0.f, d1 = 0.f;
      const float2* mp = &r12lds[(16 * h) * 128 + j];
#pragma unroll
      for (int n = 0; n < 16; n++) {
        float2 rr = mp[n * 128];                 // stride-8B b64, conflict-free
        float2 v2 = vs2[16 * h + n];             // broadcast read
        float q0 = __builtin_amdgcn_rcpf(1.f + __builtin_amdgcn_exp2f(fmaf(-rr.x, v2.x, rr.y)));
        n0 = fmaf(vw[n], q0, n0); d0 = fmaf(fabsf(vw[n]), q0, d0);
        float q1 = __builtin_amdgcn_rcpf(1.f + __builtin_amdgcn_exp2f(fmaf(-rr.x, v2.y, rr.y)));
        n1 = fmaf(vw[n], q1, n1); d1 = fmaf(fabsf(vw[n]), q1, d1);
      }
      psum[h][j] = make_float4(n0, d0, n1, d1);
      __syncthreads();
      if (h == 0) {                              // wave-uniform
        float4 a0 = psum[0][j], a1 = psum[1][j], a2 = psum[2][j], a3 = psum[3][j];
        float4 a4 = psum[4][j], a5 = psum[5][j], a6 = psum[6][j], a7 = psum[7][j];
        float wn0 = sn0 + a0.x + a1.x + a2.x + a3.x + a4.x + a5.x + a6.x + a7.x;
        float wd0 = sd0 + a0.y + a1.y + a2.y + a3.y + a4.y + a5.y + a6.y + a7.y;
        float wn1 = sn1 + a0.z + a1.z + a2.z + a3.z + a4.z + a5.z + a6.z + a7.z;
        float wd1 = sd1 + a0.w + a1.w + a2.w + a3.w + a4.w + a5.w + a6.w + a7.w;
        // NR-refined rcp (den > 1.5 always; ~1ulp vs IEEE div)
        float den0 = cgl + wd0, den1 = cgl + wd1;
        float i0 = __builtin_amdgcn_rcpf(den0); i0 = i0 * fmaf(-den0, i0, 2.f);
        float i1 = __builtin_amdgcn_rcpf(den1); i1 = i1 * fmaf(-den1, i1, 2.f);
        vj0 = (fmaf(cmj, vj0, gvl) + wn0) * i0;
        vj1 = (fmaf(cmj, vj1, gvl) + wn1) * i1;
        vs2[j] = make_float2(vj0, vj1);
      }
      __syncthreads();
    }
  }

  // ---- MLP head (naive pattern: LDS red + sequential final sum) ----
  if (tid < 128) {
    int g = tid >> 6, d = tid & 63;
    float acc = fc1_b[d];
    for (int u = 0; u < 128; u++) {
      float2 v2 = vs2[u];
      acc = fmaf(g ? v2.y : v2.x, fc1_w[d * 128 + u], acc);
    }
    red[g][d] = fmaxf(acc, 0.f) * fc2_w[d];
  }
  __syncthreads();
  if (tid < 2) {
    float s = fc2_b[0];
    for (int d = 0; d < 64; d++) s += red[tid][d];
    out[b0 + tid] = s;
  }
}

// ------------------------------- launcher ----------------------------------
extern "C" void kernel_launch(void* const* d_in, const int* in_sizes, int n_in,
                              void* d_out, int out_size, void* d_ws, size_t ws_size,
                              hipStream_t stream) {
  (void)in_sizes; (void)n_in; (void)out_size; (void)ws_size;
  char* ws = (char*)d_ws;
  // Proven 32MB envelope, time-multiplexed:
  //   P1 [0,16M) live conv1->conv2; tables [0,448K) after conv2 (prep);
  //   feats [16M,32M) live conv2->lnn.
  float*  P1   = (float*)(ws);
  float*  feats= (float*)(ws + (16 << 20));
  float2* R12  = (float2*)(ws + 0);             // 128KB
  float*  VT   = (float*)(ws + (128 << 10));    // 64KB
  float4* S4   = (float4*)(ws + (192 << 10));   // 256KB -> ends 448KB

  conv1_kernel<<<512, 512, 0, stream>>>((const float*)d_in[0],
      (const float*)d_in[1], (const float*)d_in[2], P1);
  conv2_kernel<<<512, 512, 0, stream>>>(P1,
      (const float*)d_in[3], (const float*)d_in[4], feats);
  prep_kernel<<<64, 256, 0, stream>>>(
      (const float*)d_in[7], (const float*)d_in[8],
      (const float*)d_in[9], (const float*)d_in[10],
      (const float*)d_in[11], (const float*)d_in[12],
      (const float*)d_in[13], (const float*)d_in[14],
      (const float*)d_in[5], (const float*)d_in[6],
      R12, VT, S4);
  lnn_kernel<<<256, 1024, 0, stream>>>(R12, VT, S4, feats,
      (const float*)d_in[17], (const float*)d_in[16], (const float*)d_in[15],
      (const float*)d_in[18], (const float*)d_in[19],
      (const float*)d_in[20], (const float*)d_in[21],
      (float*)d_out);
}